// Round 7
// baseline (266.965 us; speedup 1.0000x reference)
//
#include <hip/hip_runtime.h>
#include <hip/hip_bf16.h>
#include <hip/hip_fp16.h>

#define N_ 50000
#define E_ 800000
#define D_ 128
#define L_ 3

#define GG 782            // gemm blocks: ceil(50000/64)
#define NB 391            // dst buckets of 128 nodes: ceil(50000/128)
#define BCAP 3072         // per-bucket capacity (mean 2046, sd ~45 -> +22 sigma, safe)
#define PB 200            // partition blocks
#define PE 4000           // edges per partition block (PB*PE == E_)

typedef _Float16 half8 __attribute__((ext_vector_type(8)));
typedef float f32x4 __attribute__((ext_vector_type(4)));

// ---------------- helpers ----------------

__device__ inline float4 hcvt(uint2 u) {   // 4 packed fp16 -> float4
    __half2 h0 = *(__half2*)&u.x;
    __half2 h1 = *(__half2*)&u.y;
    float2 f0 = __half22float2(h0);
    float2 f1 = __half22float2(h1);
    return make_float4(f0.x, f0.y, f1.x, f1.y);
}

__device__ inline unsigned pkh(float a, float b) {  // 2 fp32 -> packed fp16 (RTNE)
    __half2 h = __floats2half2_rn(a, b);
    return *(unsigned*)&h;
}

__device__ inline unsigned short pkh1(float a) {
    _Float16 h = (_Float16)a;
    return *(unsigned short*)&h;
}

// ---------------- k_part: bucket-partition edges ----------------
// blocks [0,PB): partition PE edges each into NB dst-buckets via LDS histogram;
// one global atomicAdd per (block,bucket). Packed word: (dst&127)<<16 | src.
// blocks [PB, PB+3): W transpose layer (b-PB) fp32->fp16.

__global__ __launch_bounds__(256) void k_part(const int* __restrict__ src,
                                              const int* __restrict__ dst,
                                              const float* __restrict__ Ws,
                                              unsigned short* __restrict__ Wb,
                                              int* __restrict__ bucket_cnt,
                                              unsigned int* __restrict__ binned) {
    int b = blockIdx.x;
    if (b >= PB) {
        int l = b - PB;                    // 0,1,2
        const float* Wl = Ws + l * 16384;
        unsigned short* Wo = Wb + l * 16384;
        for (int i = threadIdx.x; i < 16384; i += 256) {
            int n = i >> 7, k = i & 127;
            Wo[n * 128 + k] = pkh1(Wl[k * 128 + n]);
        }
        return;
    }
    __shared__ int hcnt[NB];
    __shared__ int hbase[NB];
    int t = threadIdx.x;
    for (int i = t; i < NB; i += 256) hcnt[i] = 0;
    __syncthreads();
    int e0 = b * PE;
    int dreg[16], sreg[16], oreg[16];
#pragma unroll
    for (int it = 0; it < 16; ++it) {
        int i = t + it * 256;
        if (i < PE) {
            int e = e0 + i;
            int d = dst[e];
            dreg[it] = d;
            sreg[it] = src[e];
            oreg[it] = atomicAdd(&hcnt[d >> 7], 1);   // LDS atomic
        }
    }
    __syncthreads();
    for (int i = t; i < NB; i += 256) {
        int c = hcnt[i];
        hbase[i] = c ? atomicAdd(&bucket_cnt[i], c) : 0;   // one global atomic per (block,bin)
    }
    __syncthreads();
#pragma unroll
    for (int it = 0; it < 16; ++it) {
        int i = t + it * 256;
        if (i < PE) {
            int d = dreg[it];
            int bk = d >> 7;
            binned[bk * BCAP + hbase[bk] + oreg[it]] =
                ((unsigned)(d & 127) << 16) | (unsigned)sreg[it];
        }
    }
}

// ---------------- bin_body: per-bucket CSR finalize (zero global atomics) ----------------
// Computes its own exclusive bucket prefix (391 reads + wave reduce) -- no k_bscan;
// this work hides under the co-dispatched GEMM blocks.

__device__ __forceinline__ void bin_body(const unsigned int* __restrict__ binned,
                                         const int* __restrict__ bucket_cnt,
                                         int* __restrict__ row_ptr,
                                         float* __restrict__ dis,
                                         int* __restrict__ csr_src, int b) {
    __shared__ int h[128];
    __shared__ int hs[128];
    __shared__ int wtot[4];
    int t = threadIdx.x;
    int lane = t & 63, wid = t >> 6;

    // exclusive prefix over bucket counts: base = sum bucket_cnt[0..b)
    int part = 0;
    for (int i = t; i < b; i += 256) part += bucket_cnt[i];
#pragma unroll
    for (int o = 32; o > 0; o >>= 1) part += __shfl_down(part, o, 64);
    if (lane == 0) wtot[wid] = part;
    if (t < 128) h[t] = 0;
    __syncthreads();
    int base = wtot[0] + wtot[1] + wtot[2] + wtot[3];
    __syncthreads();           // wtot reused below by the 128-scan

    int cnt = bucket_cnt[b];
    const unsigned int* bp = binned + b * BCAP;
    unsigned int pk[12];
    int off[12];
#pragma unroll
    for (int it = 0; it < 12; ++it) {
        int i = t + it * 256;
        if (i < cnt) {
            unsigned int p = bp[i];
            pk[it] = p;
            off[it] = atomicAdd(&h[p >> 16], 1);    // LDS atomic
        }
    }
    __syncthreads();
    // exclusive scan of h[0..127] (waves 0/1 carry data)
    int v = (t < 128) ? h[t] : 0;
    int inc = v;
#pragma unroll
    for (int o = 1; o < 64; o <<= 1) {
        int u = __shfl_up(inc, o);
        if (lane >= o) inc += u;
    }
    if (lane == 63 && wid < 2) wtot[wid] = inc;
    __syncthreads();
    if (wid == 1) inc += wtot[0];
    if (t < 128) {
        hs[t] = inc - v;
        int node = b * 128 + t;
        if (node < N_) {
            dis[node] = rsqrtf((float)v + 1.0f);
            row_ptr[node] = base + (inc - v);
        }
    }
    if (b == 0 && t == 0) row_ptr[N_] = E_;
    __syncthreads();
#pragma unroll
    for (int it = 0; it < 12; ++it) {
        int i = t + it * 256;
        if (i < cnt) {
            unsigned int p = pk[it];
            csr_src[base + hs[p >> 16] + off[it]] = (int)(p & 0xFFFFu);
        }
    }
}

// ---------------- GEMM body ----------------
// disp != null: epilogue scales row r by disp[r] (layers 1/2; layer 0 can't --
//               dis is produced by sibling bin blocks of the same kernel).
// If st != null: x_row = relu(a*Xin + b) (+ resH fp16), side-written to xoutH (fp16).
// Output: Hb = fp16( [dis *] (x @ W) ), row-major [N][128].

__device__ __forceinline__ void gemm_body(const float* __restrict__ Xin,
                                          const unsigned short* __restrict__ Wb,
                                          const float* __restrict__ disp,
                                          uint4* __restrict__ Hb,
                                          const float* __restrict__ st,
                                          const float* __restrict__ gamma,
                                          const float* __restrict__ beta,
                                          const unsigned short* __restrict__ resH,
                                          unsigned short* __restrict__ xoutH,
                                          int blk) {
    __shared__ unsigned short wt[128 * 136];   // W^T fp16, padded stride 136
    __shared__ unsigned short xb[64 * 136];    // X tile fp16 (reused for C repack)
    __shared__ float sab[256];
    int t  = threadIdx.x;
    int r0 = blk * 64;

    if (st) {
        if (t < 128) {
            float s = 0.f, s2 = 0.f;
#pragma unroll
            for (int k = 0; k < 8; ++k) {
                s  += st[k * 256 + t];
                s2 += st[k * 256 + 128 + t];
            }
            float mean = s * (1.0f / N_);
            float var  = s2 * (1.0f / N_) - mean * mean;
            float a = gamma[t] * rsqrtf(var + 1e-5f);
            sab[t]       = a;
            sab[128 + t] = beta[t] - mean * a;
        }
        __syncthreads();
    }

    // stage W^T (2048 uint4, 8 per thread, coalesced)
#pragma unroll
    for (int j = 0; j < 8; ++j) {
        int i = t + 256 * j;
        int row = i >> 4, c16 = i & 15;
        *(uint4*)&wt[row * 136 + c16 * 8] = ((const uint4*)Wb)[i];
    }
    // stage X: fp32 -> (affine/relu/res) -> fp16 LDS (+ fp16 side-write)
#pragma unroll
    for (int j = 0; j < 8; ++j) {
        int g   = t + 256 * j;          // float4 index among 64*32
        int row = g >> 5;
        int c4  = (g & 31) * 4;
        int gr  = r0 + row;
        float4 v = make_float4(0.f, 0.f, 0.f, 0.f);
        if (gr < N_) {
            v = *(const float4*)(Xin + gr * 128 + c4);
            if (st) {
                v.x = fmaxf(sab[c4] * v.x + sab[128 + c4], 0.f);
                v.y = fmaxf(sab[c4 + 1] * v.y + sab[128 + c4 + 1], 0.f);
                v.z = fmaxf(sab[c4 + 2] * v.z + sab[128 + c4 + 2], 0.f);
                v.w = fmaxf(sab[c4 + 3] * v.w + sab[128 + c4 + 3], 0.f);
                if (resH) {
                    float4 rr = hcvt(*(const uint2*)(resH + gr * 128 + c4));
                    v.x += rr.x; v.y += rr.y; v.z += rr.z; v.w += rr.w;
                }
            }
        }
        uint2 p;
        p.x = pkh(v.x, v.y);
        p.y = pkh(v.z, v.w);
        if (st && gr < N_) *(uint2*)(xoutH + gr * 128 + c4) = p;
        *(uint2*)&xb[row * 136 + c4] = p;
    }
    __syncthreads();

    int wv   = t >> 6;
    int lane = t & 63;
    int ln   = lane & 15;
    int quad = lane >> 4;

    const unsigned short* arow = &xb[(wv * 16 + ln) * 136 + quad * 8];
    half8 af[4];
#pragma unroll
    for (int ks = 0; ks < 4; ++ks) af[ks] = *(const half8*)(arow + ks * 32);

    f32x4 acc[8];
#pragma unroll
    for (int ct = 0; ct < 8; ++ct) acc[ct] = (f32x4){0.f, 0.f, 0.f, 0.f};

#pragma unroll
    for (int ct = 0; ct < 8; ++ct) {
        const unsigned short* wp = &wt[(ct * 16 + ln) * 136 + quad * 8];
#pragma unroll
        for (int ks = 0; ks < 4; ++ks) {
            half8 bf = *(const half8*)(wp + ks * 32);
            acc[ct] = __builtin_amdgcn_mfma_f32_16x16x32_f16(af[ks], bf, acc[ct], 0, 0, 0);
        }
    }

    // epilogue: [dis-scale], fp16, repack via LDS (xb reused), coalesced uint4 store
    float dr[4] = {1.f, 1.f, 1.f, 1.f};
    if (disp) {
#pragma unroll
        for (int reg = 0; reg < 4; ++reg) {
            int r = r0 + wv * 16 + quad * 4 + reg;
            dr[reg] = disp[r < N_ ? r : (N_ - 1)];
        }
    }
    __syncthreads();   // xb reuse
#pragma unroll
    for (int ct = 0; ct < 8; ++ct) {
#pragma unroll
        for (int reg = 0; reg < 4; ++reg) {
            int lrow = wv * 16 + quad * 4 + reg;
            xb[lrow * 136 + ct * 16 + ln] = pkh1(acc[ct][reg] * dr[reg]);
        }
    }
    __syncthreads();
#pragma unroll
    for (int j = 0; j < 4; ++j) {
        int i = t + 256 * j;       // uint4 among 64*16
        int row = i >> 4, c16 = i & 15;
        int gr = r0 + row;
        if (gr < N_) Hb[gr * 16 + c16] = *(uint4*)&xb[row * 136 + c16 * 8];
    }
}

// ---------------- k_fillg: CSR finalize (blocks [0,NB)) + layer-0 GEMM ----------------

__global__ __launch_bounds__(256) void k_fillg(const unsigned int* __restrict__ binned,
                                               const int* __restrict__ bucket_cnt,
                                               int* __restrict__ row_ptr,
                                               float* __restrict__ dis,
                                               int* __restrict__ csr_src,
                                               const float* __restrict__ x,
                                               const unsigned short* __restrict__ Wb,
                                               uint4* __restrict__ Hb) {
    int b = blockIdx.x;
    if (b < NB) {
        bin_body(binned, bucket_cnt, row_ptr, dis, csr_src, b);
    } else {
        gemm_body(x, Wb, nullptr, Hb, nullptr, nullptr, nullptr, nullptr,
                  nullptr, b - NB);
    }
}

// ---------------- k_gemm: layers 1/2 (fp32 AGG input, dis-scaled Hb output) ----------------

__global__ __launch_bounds__(256) void k_gemm(const float* __restrict__ Xin,
                                              const unsigned short* __restrict__ Wb,
                                              const float* __restrict__ disp,
                                              uint4* __restrict__ Hb,
                                              const float* __restrict__ st,
                                              const float* __restrict__ gamma,
                                              const float* __restrict__ beta,
                                              const unsigned short* __restrict__ resH,
                                              unsigned short* __restrict__ xoutH) {
    gemm_body(Xin, Wb, disp, Hb, st, gamma, beta, resH, xoutH, blockIdx.x);
}

// ---------------- Aggregation + fused BN stats ----------------
// 16 nodes / 256-thread block; 16 lanes/node, 8 features (uint4) each.
// Batch-8 gathers (8 uint4 in flight/lane) + next-chunk csr prefetch.
// ALL loads/stores cached (NT fully reverted -- R6 lesson: AGG is producer-consumer).
// SCALED: Hb rows carry dis[src] (gemm epilogue) -> plain adds, no dis gather.
// !SCALED (layer 0): Hb unscaled, gather dis[src] per edge.

template <bool SCALED>
__global__ __launch_bounds__(256) void k_agg(const uint4* __restrict__ Hb,
                                             const int* __restrict__ row_ptr,
                                             const int* __restrict__ csr_src,
                                             const float* __restrict__ dis,
                                             const float* __restrict__ bias,
                                             float4* __restrict__ AGG,
                                             float* __restrict__ stats2) {
    int tid  = threadIdx.x;
    int sub  = tid >> 4;          // 0..15 node in block
    int lane = tid & 15;          // feature group: 8 feats
    int node = blockIdx.x * 16 + sub;

    int beg = row_ptr[node], end = row_ptr[node + 1];
    float dn = dis[node];
    uint4 su = Hb[node * 16 + lane];
    float4 f0s = hcvt(make_uint2(su.x, su.y));
    float4 f1s = hcvt(make_uint2(su.z, su.w));
    float4 acc0, acc1;
    if constexpr (SCALED) {
        acc0 = f0s; acc1 = f1s;
    } else {
        acc0.x = dn * f0s.x; acc0.y = dn * f0s.y; acc0.z = dn * f0s.z; acc0.w = dn * f0s.w;
        acc1.x = dn * f1s.x; acc1.y = dn * f1s.y; acc1.z = dn * f1s.z; acc1.w = dn * f1s.w;
    }

    int c = beg;
    int idx = 0; float dsv = 0.f;
    {
        int m0 = end - c; if (m0 > 16) m0 = 16;
        if (lane < m0) {
            idx = csr_src[c + lane];
            if constexpr (!SCALED) dsv = dis[idx];
        }
    }
    while (c < end) {
        int m = end - c; if (m > 16) m = 16;
        // prefetch next chunk's indices (and dis for layer 0), plain cached loads
        int nidx = 0; float ndsv = 0.f;
        int nm = end - (c + 16); if (nm > 16) nm = 16;
        if (lane < nm) {
            nidx = csr_src[c + 16 + lane];
            if constexpr (!SCALED) ndsv = dis[nidx];
        }
        int j = 0;
        for (; j + 8 <= m; j += 8) {
            int s[8]; float d[8]; uint4 a[8];
#pragma unroll
            for (int k = 0; k < 8; ++k) {
                s[k] = __shfl(idx, j + k, 16);
                if constexpr (!SCALED) d[k] = __shfl(dsv, j + k, 16);
            }
#pragma unroll
            for (int k = 0; k < 8; ++k) a[k] = Hb[s[k] * 16 + lane];
#pragma unroll
            for (int k = 0; k < 8; ++k) {
                float4 f0 = hcvt(make_uint2(a[k].x, a[k].y));
                float4 f1 = hcvt(make_uint2(a[k].z, a[k].w));
                if constexpr (SCALED) {
                    acc0.x += f0.x; acc0.y += f0.y; acc0.z += f0.z; acc0.w += f0.w;
                    acc1.x += f1.x; acc1.y += f1.y; acc1.z += f1.z; acc1.w += f1.w;
                } else {
                    acc0.x += d[k] * f0.x; acc0.y += d[k] * f0.y;
                    acc0.z += d[k] * f0.z; acc0.w += d[k] * f0.w;
                    acc1.x += d[k] * f1.x; acc1.y += d[k] * f1.y;
                    acc1.z += d[k] * f1.z; acc1.w += d[k] * f1.w;
                }
            }
        }
        for (; j + 4 <= m; j += 4) {
            int s[4]; float d[4]; uint4 a[4];
#pragma unroll
            for (int k = 0; k < 4; ++k) {
                s[k] = __shfl(idx, j + k, 16);
                if constexpr (!SCALED) d[k] = __shfl(dsv, j + k, 16);
            }
#pragma unroll
            for (int k = 0; k < 4; ++k) a[k] = Hb[s[k] * 16 + lane];
#pragma unroll
            for (int k = 0; k < 4; ++k) {
                float4 f0 = hcvt(make_uint2(a[k].x, a[k].y));
                float4 f1 = hcvt(make_uint2(a[k].z, a[k].w));
                if constexpr (SCALED) {
                    acc0.x += f0.x; acc0.y += f0.y; acc0.z += f0.z; acc0.w += f0.w;
                    acc1.x += f1.x; acc1.y += f1.y; acc1.z += f1.z; acc1.w += f1.w;
                } else {
                    acc0.x += d[k] * f0.x; acc0.y += d[k] * f0.y;
                    acc0.z += d[k] * f0.z; acc0.w += d[k] * f0.w;
                    acc1.x += d[k] * f1.x; acc1.y += d[k] * f1.y;
                    acc1.z += d[k] * f1.z; acc1.w += d[k] * f1.w;
                }
            }
        }
        for (; j < m; ++j) {
            int s0 = __shfl(idx, j, 16);
            float d0 = 1.f;
            if constexpr (!SCALED) d0 = __shfl(dsv, j, 16);
            uint4 a0 = Hb[s0 * 16 + lane];
            float4 f0 = hcvt(make_uint2(a0.x, a0.y));
            float4 f1 = hcvt(make_uint2(a0.z, a0.w));
            if constexpr (SCALED) {
                acc0.x += f0.x; acc0.y += f0.y; acc0.z += f0.z; acc0.w += f0.w;
                acc1.x += f1.x; acc1.y += f1.y; acc1.z += f1.z; acc1.w += f1.w;
            } else {
                acc0.x += d0 * f0.x; acc0.y += d0 * f0.y;
                acc0.z += d0 * f0.z; acc0.w += d0 * f0.w;
                acc1.x += d0 * f1.x; acc1.y += d0 * f1.y;
                acc1.z += d0 * f1.z; acc1.w += d0 * f1.w;
            }
        }
        idx = nidx; dsv = ndsv; c += 16;
    }

    float4 b0 = *(const float4*)(bias + lane * 8);
    float4 b1 = *(const float4*)(bias + lane * 8 + 4);
    float4 r0, r1;
    r0.x = dn * acc0.x + b0.x; r0.y = dn * acc0.y + b0.y;
    r0.z = dn * acc0.z + b0.z; r0.w = dn * acc0.w + b0.w;
    r1.x = dn * acc1.x + b1.x; r1.y = dn * acc1.y + b1.y;
    r1.z = dn * acc1.z + b1.z; r1.w = dn * acc1.w + b1.w;
    AGG[node * 32 + lane * 2]     = r0;
    AGG[node * 32 + lane * 2 + 1] = r1;

    __shared__ float sbuf[16][128];
    float4* sp = (float4*)&sbuf[sub][lane * 8];
    sp[0] = r0; sp[1] = r1;
    __syncthreads();
    if (tid < 128) {
        float s = 0.f, s2 = 0.f;
#pragma unroll
        for (int k = 0; k < 16; ++k) {
            float v = sbuf[k][tid];
            s += v; s2 += v * v;
        }
        float* stp = stats2 + (blockIdx.x & 7) * 256;
        atomicAdd(&stp[tid], s);
        atomicAdd(&stp[128 + tid], s2);
    }
}

// ---------------- Final normalize (layer 2): out = resH + affine(AGG) ----------------

__global__ __launch_bounds__(256) void k_normF(const float4* __restrict__ AGG,
                                               const unsigned short* __restrict__ resH,
                                               const float* __restrict__ st,
                                               const float* __restrict__ gamma,
                                               const float* __restrict__ beta,
                                               float4* __restrict__ OUT) {
    __shared__ float sab[256];
    int t = threadIdx.x;
    if (t < 128) {
        float s = 0.f, s2 = 0.f;
#pragma unroll
        for (int k = 0; k < 8; ++k) {
            s  += st[k * 256 + t];
            s2 += st[k * 256 + 128 + t];
        }
        float mean = s * (1.0f / N_);
        float var  = s2 * (1.0f / N_) - mean * mean;
        float a = gamma[t] * rsqrtf(var + 1e-5f);
        sab[t]       = a;
        sab[128 + t] = beta[t] - mean * a;
    }
    __syncthreads();
    for (int i = blockIdx.x * 256 + t; i < N_ * 32; i += gridDim.x * 256) {
        int f4 = (i & 31) * 4;
        float4 v = AGG[i];
        float4 rr = hcvt(((const uint2*)resH)[i]);
        v.x = sab[f4] * v.x + sab[128 + f4] + rr.x;
        v.y = sab[f4 + 1] * v.y + sab[128 + f4 + 1] + rr.y;
        v.z = sab[f4 + 2] * v.z + sab[128 + f4 + 2] + rr.z;
        v.w = sab[f4 + 3] * v.w + sab[128 + f4 + 3] + rr.w;
        OUT[i] = v;
    }
}

// ---------------- Launch ----------------

extern "C" void kernel_launch(void* const* d_in, const int* in_sizes, int n_in,
                              void* d_out, int out_size, void* d_ws, size_t ws_size,
                              hipStream_t stream) {
    const float* x      = (const float*)d_in[0];
    const int*   ei     = (const int*)d_in[1];
    const float* Ws     = (const float*)d_in[2];
    const float* bs     = (const float*)d_in[3];
    const float* gammas = (const float*)d_in[4];
    const float* betas  = (const float*)d_in[5];
    float* out = (float*)d_out;

    const int* src = ei;
    const int* dst = ei + E_;

    char* w = (char*)d_ws;
    float* stats2      = (float*)(w + 0);          // 3*2048 floats   [0, 24576)
    int*   bucket_cnt  = (int*)(w + 24576);        // 391 ints        [24576, 26140)
    int*   row_ptr     = (int*)(w + 27712);        // N+1 ints        [27712, 227716)
    float* dis         = (float*)(w + 227728);     // N floats        [227728, 427728)
    int*   csr_src     = (int*)(w + 427728);       // E ints          [427728, 3627728)
    uint4* Hb          = (uint4*)(w + 3627776);    // N*D fp16 12.8MB [3627776, 16427776)
    unsigned short* XBh = (unsigned short*)(w + 16427776); // N*D fp16 [16427776, 29227776)
    unsigned short* Wb  = (unsigned short*)(w + 29227776); // 3*16384 fp16 [.., 29326080)
    float* AGG = out;                              // AGG lives in d_out (fp32)

    // binned edge slots alias XBh (dead until gemm1 writes it): 391*3072*4B = 4.8MB
    unsigned int* binned = (unsigned int*)XBh;

    hipMemsetAsync(d_ws, 0, 26144, stream);        // stats2 + bucket_cnt

    // bucket partition (+ W fp16-transpose, 3 extra blocks)
    k_part<<<PB + 3, 256, 0, stream>>>(src, dst, Ws, Wb, bucket_cnt, binned);
    // per-bucket CSR finalize (self-prefix; dis/row_ptr/csr_src) fused with layer-0 GEMM
    k_fillg<<<NB + GG, 256, 0, stream>>>(binned, bucket_cnt, row_ptr,
                                         dis, csr_src, x, Wb, Hb);

    // L0: agg (unscaled Hb: gather dis) -> AGG(d_out), st0
    k_agg<false><<<N_ / 16, 256, 0, stream>>>(Hb, row_ptr, csr_src, dis, bs,
                                              (float4*)AGG, stats2);
    // L1: gemm(AGG | affine0+relu -> XBh) -> dis-scaled Hb ; agg -> AGG, st1
    k_gemm<<<GG, 256, 0, stream>>>(AGG, Wb + 16384, dis, Hb,
                                   stats2, gammas, betas, nullptr, XBh);
    k_agg<true><<<N_ / 16, 256, 0, stream>>>(Hb, row_ptr, csr_src, dis, bs + D_,
                                             (float4*)AGG, stats2 + 2048);
    // L2: gemm(AGG | affine1+relu + res XBh -> XBh) -> dis-scaled Hb ; agg -> AGG, st2
    k_gemm<<<GG, 256, 0, stream>>>(AGG, Wb + 32768, dis, Hb,
                                   stats2 + 2048, gammas + D_, betas + D_, XBh, XBh);
    k_agg<true><<<N_ / 16, 256, 0, stream>>>(Hb, row_ptr, csr_src, dis, bs + 2 * D_,
                                             (float4*)AGG, stats2 + 4096);
    // final: out = x2 + affine2(AGG)   (in-place on d_out)
    k_normF<<<1024, 256, 0, stream>>>((const float4*)AGG, XBh,
                                      stats2 + 4096, gammas + 2 * D_, betas + 2 * D_,
                                      (float4*)out);
}

// Round 8
// 257.408 us; speedup vs baseline: 1.0371x; 1.0371x over previous
//
#include <hip/hip_runtime.h>
#include <hip/hip_bf16.h>
#include <hip/hip_fp16.h>

#define N_ 50000
#define E_ 800000
#define D_ 128
#define L_ 3

#define GG 782            // gemm blocks: ceil(50000/64)
#define NB 391            // dst buckets of 128 nodes: ceil(50000/128)
#define BCAP 3072         // per-bucket capacity (mean 2046, sd ~45 -> +22 sigma, safe)
#define PB 200            // partition blocks
#define PE 4000           // edges per partition block (PB*PE == E_)

typedef _Float16 half8 __attribute__((ext_vector_type(8)));
typedef float f32x4 __attribute__((ext_vector_type(4)));

// ---------------- helpers ----------------

__device__ inline float4 hcvt(uint2 u) {   // 4 packed fp16 -> float4
    __half2 h0 = *(__half2*)&u.x;
    __half2 h1 = *(__half2*)&u.y;
    float2 f0 = __half22float2(h0);
    float2 f1 = __half22float2(h1);
    return make_float4(f0.x, f0.y, f1.x, f1.y);
}

__device__ inline unsigned pkh(float a, float b) {  // 2 fp32 -> packed fp16 (RTNE)
    __half2 h = __floats2half2_rn(a, b);
    return *(unsigned*)&h;
}

__device__ inline unsigned short pkh1(float a) {
    _Float16 h = (_Float16)a;
    return *(unsigned short*)&h;
}

// ---------------- k_part: bucket-partition edges ----------------
// blocks [0,PB): partition PE edges each into NB dst-buckets via LDS histogram;
// one global atomicAdd per (block,bucket). Packed word: (dst&127)<<16 | src.
// blocks [PB, PB+3): W transpose layer (b-PB) fp32->fp16.

__global__ __launch_bounds__(256) void k_part(const int* __restrict__ src,
                                              const int* __restrict__ dst,
                                              const float* __restrict__ Ws,
                                              unsigned short* __restrict__ Wb,
                                              int* __restrict__ bucket_cnt,
                                              unsigned int* __restrict__ binned) {
    int b = blockIdx.x;
    if (b >= PB) {
        int l = b - PB;                    // 0,1,2
        const float* Wl = Ws + l * 16384;
        unsigned short* Wo = Wb + l * 16384;
        for (int i = threadIdx.x; i < 16384; i += 256) {
            int n = i >> 7, k = i & 127;
            Wo[n * 128 + k] = pkh1(Wl[k * 128 + n]);
        }
        return;
    }
    __shared__ int hcnt[NB];
    __shared__ int hbase[NB];
    int t = threadIdx.x;
    for (int i = t; i < NB; i += 256) hcnt[i] = 0;
    __syncthreads();
    int e0 = b * PE;
    int dreg[16], sreg[16], oreg[16];
#pragma unroll
    for (int it = 0; it < 16; ++it) {
        int i = t + it * 256;
        if (i < PE) {
            int e = e0 + i;
            int d = dst[e];
            dreg[it] = d;
            sreg[it] = src[e];
            oreg[it] = atomicAdd(&hcnt[d >> 7], 1);   // LDS atomic
        }
    }
    __syncthreads();
    for (int i = t; i < NB; i += 256) {
        int c = hcnt[i];
        hbase[i] = c ? atomicAdd(&bucket_cnt[i], c) : 0;   // one global atomic per (block,bin)
    }
    __syncthreads();
#pragma unroll
    for (int it = 0; it < 16; ++it) {
        int i = t + it * 256;
        if (i < PE) {
            int d = dreg[it];
            int bk = d >> 7;
            binned[bk * BCAP + hbase[bk] + oreg[it]] =
                ((unsigned)(d & 127) << 16) | (unsigned)sreg[it];
        }
    }
}

// ---------------- bin_body: per-bucket CSR finalize (zero global atomics) ----------------
// Computes its own exclusive bucket prefix (391 reads + wave reduce) -- no k_bscan;
// this work hides under the co-dispatched GEMM blocks.

__device__ __forceinline__ void bin_body(const unsigned int* __restrict__ binned,
                                         const int* __restrict__ bucket_cnt,
                                         int* __restrict__ row_ptr,
                                         float* __restrict__ dis,
                                         int* __restrict__ csr_src, int b) {
    __shared__ int h[128];
    __shared__ int hs[128];
    __shared__ int wtot[4];
    int t = threadIdx.x;
    int lane = t & 63, wid = t >> 6;

    // exclusive prefix over bucket counts: base = sum bucket_cnt[0..b)
    int part = 0;
    for (int i = t; i < b; i += 256) part += bucket_cnt[i];
#pragma unroll
    for (int o = 32; o > 0; o >>= 1) part += __shfl_down(part, o, 64);
    if (lane == 0) wtot[wid] = part;
    if (t < 128) h[t] = 0;
    __syncthreads();
    int base = wtot[0] + wtot[1] + wtot[2] + wtot[3];
    __syncthreads();           // wtot reused below by the 128-scan

    int cnt = bucket_cnt[b];
    const unsigned int* bp = binned + b * BCAP;
    unsigned int pk[12];
    int off[12];
#pragma unroll
    for (int it = 0; it < 12; ++it) {
        int i = t + it * 256;
        if (i < cnt) {
            unsigned int p = bp[i];
            pk[it] = p;
            off[it] = atomicAdd(&h[p >> 16], 1);    // LDS atomic
        }
    }
    __syncthreads();
    // exclusive scan of h[0..127] (waves 0/1 carry data)
    int v = (t < 128) ? h[t] : 0;
    int inc = v;
#pragma unroll
    for (int o = 1; o < 64; o <<= 1) {
        int u = __shfl_up(inc, o);
        if (lane >= o) inc += u;
    }
    if (lane == 63 && wid < 2) wtot[wid] = inc;
    __syncthreads();
    if (wid == 1) inc += wtot[0];
    if (t < 128) {
        hs[t] = inc - v;
        int node = b * 128 + t;
        if (node < N_) {
            dis[node] = rsqrtf((float)v + 1.0f);
            row_ptr[node] = base + (inc - v);
        }
    }
    if (b == 0 && t == 0) row_ptr[N_] = E_;
    __syncthreads();
#pragma unroll
    for (int it = 0; it < 12; ++it) {
        int i = t + it * 256;
        if (i < cnt) {
            unsigned int p = pk[it];
            csr_src[base + hs[p >> 16] + off[it]] = (int)(p & 0xFFFFu);
        }
    }
}

// ---------------- GEMM body ----------------
// disp != null: epilogue scales row r by disp[r] (layers 1/2; layer 0 can't --
//               dis is produced by sibling bin blocks of the same kernel).
// If st != null: x_row = relu(a*Xin + b) (+ resH fp16), side-written to xoutH (fp16).
// Output: Hb = fp16( [dis *] (x @ W) ), row-major [N][128].

__device__ __forceinline__ void gemm_body(const float* __restrict__ Xin,
                                          const unsigned short* __restrict__ Wb,
                                          const float* __restrict__ disp,
                                          uint4* __restrict__ Hb,
                                          const float* __restrict__ st,
                                          const float* __restrict__ gamma,
                                          const float* __restrict__ beta,
                                          const unsigned short* __restrict__ resH,
                                          unsigned short* __restrict__ xoutH,
                                          int blk) {
    __shared__ unsigned short wt[128 * 136];   // W^T fp16, padded stride 136
    __shared__ unsigned short xb[64 * 136];    // X tile fp16 (reused for C repack)
    __shared__ float sab[256];
    int t  = threadIdx.x;
    int r0 = blk * 64;

    if (st) {
        if (t < 128) {
            float s = 0.f, s2 = 0.f;
#pragma unroll
            for (int k = 0; k < 8; ++k) {
                s  += st[k * 256 + t];
                s2 += st[k * 256 + 128 + t];
            }
            float mean = s * (1.0f / N_);
            float var  = s2 * (1.0f / N_) - mean * mean;
            float a = gamma[t] * rsqrtf(var + 1e-5f);
            sab[t]       = a;
            sab[128 + t] = beta[t] - mean * a;
        }
        __syncthreads();
    }

    // stage W^T (2048 uint4, 8 per thread, coalesced)
#pragma unroll
    for (int j = 0; j < 8; ++j) {
        int i = t + 256 * j;
        int row = i >> 4, c16 = i & 15;
        *(uint4*)&wt[row * 136 + c16 * 8] = ((const uint4*)Wb)[i];
    }
    // stage X: fp32 -> (affine/relu/res) -> fp16 LDS (+ fp16 side-write)
#pragma unroll
    for (int j = 0; j < 8; ++j) {
        int g   = t + 256 * j;          // float4 index among 64*32
        int row = g >> 5;
        int c4  = (g & 31) * 4;
        int gr  = r0 + row;
        float4 v = make_float4(0.f, 0.f, 0.f, 0.f);
        if (gr < N_) {
            v = *(const float4*)(Xin + gr * 128 + c4);
            if (st) {
                v.x = fmaxf(sab[c4] * v.x + sab[128 + c4], 0.f);
                v.y = fmaxf(sab[c4 + 1] * v.y + sab[128 + c4 + 1], 0.f);
                v.z = fmaxf(sab[c4 + 2] * v.z + sab[128 + c4 + 2], 0.f);
                v.w = fmaxf(sab[c4 + 3] * v.w + sab[128 + c4 + 3], 0.f);
                if (resH) {
                    float4 rr = hcvt(*(const uint2*)(resH + gr * 128 + c4));
                    v.x += rr.x; v.y += rr.y; v.z += rr.z; v.w += rr.w;
                }
            }
        }
        uint2 p;
        p.x = pkh(v.x, v.y);
        p.y = pkh(v.z, v.w);
        if (st && gr < N_) *(uint2*)(xoutH + gr * 128 + c4) = p;
        *(uint2*)&xb[row * 136 + c4] = p;
    }
    __syncthreads();

    int wv   = t >> 6;
    int lane = t & 63;
    int ln   = lane & 15;
    int quad = lane >> 4;

    const unsigned short* arow = &xb[(wv * 16 + ln) * 136 + quad * 8];
    half8 af[4];
#pragma unroll
    for (int ks = 0; ks < 4; ++ks) af[ks] = *(const half8*)(arow + ks * 32);

    f32x4 acc[8];
#pragma unroll
    for (int ct = 0; ct < 8; ++ct) acc[ct] = (f32x4){0.f, 0.f, 0.f, 0.f};

#pragma unroll
    for (int ct = 0; ct < 8; ++ct) {
        const unsigned short* wp = &wt[(ct * 16 + ln) * 136 + quad * 8];
#pragma unroll
        for (int ks = 0; ks < 4; ++ks) {
            half8 bf = *(const half8*)(wp + ks * 32);
            acc[ct] = __builtin_amdgcn_mfma_f32_16x16x32_f16(af[ks], bf, acc[ct], 0, 0, 0);
        }
    }

    // epilogue: [dis-scale], fp16, repack via LDS (xb reused), coalesced uint4 store
    float dr[4] = {1.f, 1.f, 1.f, 1.f};
    if (disp) {
#pragma unroll
        for (int reg = 0; reg < 4; ++reg) {
            int r = r0 + wv * 16 + quad * 4 + reg;
            dr[reg] = disp[r < N_ ? r : (N_ - 1)];
        }
    }
    __syncthreads();   // xb reuse
#pragma unroll
    for (int ct = 0; ct < 8; ++ct) {
#pragma unroll
        for (int reg = 0; reg < 4; ++reg) {
            int lrow = wv * 16 + quad * 4 + reg;
            xb[lrow * 136 + ct * 16 + ln] = pkh1(acc[ct][reg] * dr[reg]);
        }
    }
    __syncthreads();
#pragma unroll
    for (int j = 0; j < 4; ++j) {
        int i = t + 256 * j;       // uint4 among 64*16
        int row = i >> 4, c16 = i & 15;
        int gr = r0 + row;
        if (gr < N_) Hb[gr * 16 + c16] = *(uint4*)&xb[row * 136 + c16 * 8];
    }
}

// ---------------- k_fillg: CSR finalize (blocks [0,NB)) + layer-0 GEMM ----------------

__global__ __launch_bounds__(256) void k_fillg(const unsigned int* __restrict__ binned,
                                               const int* __restrict__ bucket_cnt,
                                               int* __restrict__ row_ptr,
                                               float* __restrict__ dis,
                                               int* __restrict__ csr_src,
                                               const float* __restrict__ x,
                                               const unsigned short* __restrict__ Wb,
                                               uint4* __restrict__ Hb) {
    int b = blockIdx.x;
    if (b < NB) {
        bin_body(binned, bucket_cnt, row_ptr, dis, csr_src, b);
    } else {
        gemm_body(x, Wb, nullptr, Hb, nullptr, nullptr, nullptr, nullptr,
                  nullptr, b - NB);
    }
}

// ---------------- k_gemm: layers 1/2 (fp32 AGG input, dis-scaled Hb output) ----------------

__global__ __launch_bounds__(256) void k_gemm(const float* __restrict__ Xin,
                                              const unsigned short* __restrict__ Wb,
                                              const float* __restrict__ disp,
                                              uint4* __restrict__ Hb,
                                              const float* __restrict__ st,
                                              const float* __restrict__ gamma,
                                              const float* __restrict__ beta,
                                              const unsigned short* __restrict__ resH,
                                              unsigned short* __restrict__ xoutH) {
    gemm_body(Xin, Wb, disp, Hb, st, gamma, beta, resH, xoutH, blockIdx.x);
}

// ---------------- Aggregation + fused BN stats (round-5 structure, empirical best) ----------------
// 16 nodes / 256-thread block; 16 lanes/node, 8 features (uint4) each.
// SCALED: Hb rows carry dis[src] (gemm epilogue) -> plain adds, no dis gather.
// !SCALED (layer 0): Hb unscaled, gather dis[src] per edge.

template <bool SCALED>
__global__ __launch_bounds__(256) void k_agg(const uint4* __restrict__ Hb,
                                             const int* __restrict__ row_ptr,
                                             const int* __restrict__ csr_src,
                                             const float* __restrict__ dis,
                                             const float* __restrict__ bias,
                                             float4* __restrict__ AGG,
                                             float* __restrict__ stats2) {
    int tid  = threadIdx.x;
    int sub  = tid >> 4;          // 0..15 node in block
    int lane = tid & 15;          // feature group: 8 feats
    int node = blockIdx.x * 16 + sub;

    int beg = row_ptr[node], end = row_ptr[node + 1];
    float dn = dis[node];
    uint4 su = Hb[node * 16 + lane];
    float4 f0s = hcvt(make_uint2(su.x, su.y));
    float4 f1s = hcvt(make_uint2(su.z, su.w));
    float4 acc0, acc1;
    if constexpr (SCALED) {
        acc0 = f0s; acc1 = f1s;
    } else {
        acc0.x = dn * f0s.x; acc0.y = dn * f0s.y; acc0.z = dn * f0s.z; acc0.w = dn * f0s.w;
        acc1.x = dn * f1s.x; acc1.y = dn * f1s.y; acc1.z = dn * f1s.z; acc1.w = dn * f1s.w;
    }

    for (int c = beg; c < end; c += 16) {
        int m = end - c; if (m > 16) m = 16;
        int idx = 0; float dsv = 0.f;
        if (lane < m) {
            idx = csr_src[c + lane];
            if constexpr (!SCALED) dsv = dis[idx];
        }
        int j = 0;
        for (; j + 4 <= m; j += 4) {
            int s0 = __shfl(idx, j, 16);
            int s1 = __shfl(idx, j + 1, 16);
            int s2 = __shfl(idx, j + 2, 16);
            int s3 = __shfl(idx, j + 3, 16);
            float d0 = 1.f, d1 = 1.f, d2 = 1.f, d3 = 1.f;
            if constexpr (!SCALED) {
                d0 = __shfl(dsv, j, 16);
                d1 = __shfl(dsv, j + 1, 16);
                d2 = __shfl(dsv, j + 2, 16);
                d3 = __shfl(dsv, j + 3, 16);
            }
            uint4 a0 = Hb[s0 * 16 + lane];
            uint4 a1 = Hb[s1 * 16 + lane];
            uint4 a2 = Hb[s2 * 16 + lane];
            uint4 a3 = Hb[s3 * 16 + lane];
            float4 f00 = hcvt(make_uint2(a0.x, a0.y)), f01 = hcvt(make_uint2(a0.z, a0.w));
            float4 f10 = hcvt(make_uint2(a1.x, a1.y)), f11 = hcvt(make_uint2(a1.z, a1.w));
            float4 f20 = hcvt(make_uint2(a2.x, a2.y)), f21 = hcvt(make_uint2(a2.z, a2.w));
            float4 f30 = hcvt(make_uint2(a3.x, a3.y)), f31 = hcvt(make_uint2(a3.z, a3.w));
            if constexpr (SCALED) {
                acc0.x += f00.x + f10.x + f20.x + f30.x;
                acc0.y += f00.y + f10.y + f20.y + f30.y;
                acc0.z += f00.z + f10.z + f20.z + f30.z;
                acc0.w += f00.w + f10.w + f20.w + f30.w;
                acc1.x += f01.x + f11.x + f21.x + f31.x;
                acc1.y += f01.y + f11.y + f21.y + f31.y;
                acc1.z += f01.z + f11.z + f21.z + f31.z;
                acc1.w += f01.w + f11.w + f21.w + f31.w;
            } else {
                acc0.x += d0 * f00.x + d1 * f10.x + d2 * f20.x + d3 * f30.x;
                acc0.y += d0 * f00.y + d1 * f10.y + d2 * f20.y + d3 * f30.y;
                acc0.z += d0 * f00.z + d1 * f10.z + d2 * f20.z + d3 * f30.z;
                acc0.w += d0 * f00.w + d1 * f10.w + d2 * f20.w + d3 * f30.w;
                acc1.x += d0 * f01.x + d1 * f11.x + d2 * f21.x + d3 * f31.x;
                acc1.y += d0 * f01.y + d1 * f11.y + d2 * f21.y + d3 * f31.y;
                acc1.z += d0 * f01.z + d1 * f11.z + d2 * f21.z + d3 * f31.z;
                acc1.w += d0 * f01.w + d1 * f11.w + d2 * f21.w + d3 * f31.w;
            }
        }
        for (; j < m; ++j) {
            int s0 = __shfl(idx, j, 16);
            float d0 = 1.f;
            if constexpr (!SCALED) d0 = __shfl(dsv, j, 16);
            uint4 a0 = Hb[s0 * 16 + lane];
            float4 f00 = hcvt(make_uint2(a0.x, a0.y)), f01 = hcvt(make_uint2(a0.z, a0.w));
            if constexpr (SCALED) {
                acc0.x += f00.x; acc0.y += f00.y; acc0.z += f00.z; acc0.w += f00.w;
                acc1.x += f01.x; acc1.y += f01.y; acc1.z += f01.z; acc1.w += f01.w;
            } else {
                acc0.x += d0 * f00.x; acc0.y += d0 * f00.y;
                acc0.z += d0 * f00.z; acc0.w += d0 * f00.w;
                acc1.x += d0 * f01.x; acc1.y += d0 * f01.y;
                acc1.z += d0 * f01.z; acc1.w += d0 * f01.w;
            }
        }
    }

    float dnn = dn;
    float4 b0 = *(const float4*)(bias + lane * 8);
    float4 b1 = *(const float4*)(bias + lane * 8 + 4);
    float4 r0, r1;
    r0.x = dnn * acc0.x + b0.x; r0.y = dnn * acc0.y + b0.y;
    r0.z = dnn * acc0.z + b0.z; r0.w = dnn * acc0.w + b0.w;
    r1.x = dnn * acc1.x + b1.x; r1.y = dnn * acc1.y + b1.y;
    r1.z = dnn * acc1.z + b1.z; r1.w = dnn * acc1.w + b1.w;
    AGG[node * 32 + lane * 2]     = r0;
    AGG[node * 32 + lane * 2 + 1] = r1;

    __shared__ float sbuf[16][128];
    float4* sp = (float4*)&sbuf[sub][lane * 8];
    sp[0] = r0; sp[1] = r1;
    __syncthreads();
    if (tid < 128) {
        float s = 0.f, s2 = 0.f;
#pragma unroll
        for (int k = 0; k < 16; ++k) {
            float v = sbuf[k][tid];
            s += v; s2 += v * v;
        }
        float* stp = stats2 + (blockIdx.x & 7) * 256;
        atomicAdd(&stp[tid], s);
        atomicAdd(&stp[128 + tid], s2);
    }
}

// ---------------- Final normalize (layer 2): out = resH + affine(AGG) ----------------

__global__ __launch_bounds__(256) void k_normF(const float4* __restrict__ AGG,
                                               const unsigned short* __restrict__ resH,
                                               const float* __restrict__ st,
                                               const float* __restrict__ gamma,
                                               const float* __restrict__ beta,
                                               float4* __restrict__ OUT) {
    __shared__ float sab[256];
    int t = threadIdx.x;
    if (t < 128) {
        float s = 0.f, s2 = 0.f;
#pragma unroll
        for (int k = 0; k < 8; ++k) {
            s  += st[k * 256 + t];
            s2 += st[k * 256 + 128 + t];
        }
        float mean = s * (1.0f / N_);
        float var  = s2 * (1.0f / N_) - mean * mean;
        float a = gamma[t] * rsqrtf(var + 1e-5f);
        sab[t]       = a;
        sab[128 + t] = beta[t] - mean * a;
    }
    __syncthreads();
    for (int i = blockIdx.x * 256 + t; i < N_ * 32; i += gridDim.x * 256) {
        int f4 = (i & 31) * 4;
        float4 v = AGG[i];
        float4 rr = hcvt(((const uint2*)resH)[i]);
        v.x = sab[f4] * v.x + sab[128 + f4] + rr.x;
        v.y = sab[f4 + 1] * v.y + sab[128 + f4 + 1] + rr.y;
        v.z = sab[f4 + 2] * v.z + sab[128 + f4 + 2] + rr.z;
        v.w = sab[f4 + 3] * v.w + sab[128 + f4 + 3] + rr.w;
        OUT[i] = v;
    }
}

// ---------------- Launch ----------------

extern "C" void kernel_launch(void* const* d_in, const int* in_sizes, int n_in,
                              void* d_out, int out_size, void* d_ws, size_t ws_size,
                              hipStream_t stream) {
    const float* x      = (const float*)d_in[0];
    const int*   ei     = (const int*)d_in[1];
    const float* Ws     = (const float*)d_in[2];
    const float* bs     = (const float*)d_in[3];
    const float* gammas = (const float*)d_in[4];
    const float* betas  = (const float*)d_in[5];
    float* out = (float*)d_out;

    const int* src = ei;
    const int* dst = ei + E_;

    char* w = (char*)d_ws;
    float* stats2      = (float*)(w + 0);          // 3*2048 floats   [0, 24576)
    int*   bucket_cnt  = (int*)(w + 24576);        // 391 ints        [24576, 26140)
    int*   row_ptr     = (int*)(w + 27712);        // N+1 ints        [27712, 227716)
    float* dis         = (float*)(w + 227728);     // N floats        [227728, 427728)
    int*   csr_src     = (int*)(w + 427728);       // E ints          [427728, 3627728)
    uint4* Hb          = (uint4*)(w + 3627776);    // N*D fp16 12.8MB [3627776, 16427776)
    unsigned short* XBh = (unsigned short*)(w + 16427776); // N*D fp16 [16427776, 29227776)
    unsigned short* Wb  = (unsigned short*)(w + 29227776); // 3*16384 fp16 [.., 29326080)
    float* AGG = out;                              // AGG lives in d_out (fp32)

    // binned edge slots alias XBh (dead until gemm1 writes it): 391*3072*4B = 4.8MB
    unsigned int* binned = (unsigned int*)XBh;

    hipMemsetAsync(d_ws, 0, 26144, stream);        // stats2 + bucket_cnt

    // bucket partition (+ W fp16-transpose, 3 extra blocks)
    k_part<<<PB + 3, 256, 0, stream>>>(src, dst, Ws, Wb, bucket_cnt, binned);
    // per-bucket CSR finalize (self-prefix; dis/row_ptr/csr_src) fused with layer-0 GEMM
    k_fillg<<<NB + GG, 256, 0, stream>>>(binned, bucket_cnt, row_ptr,
                                         dis, csr_src, x, Wb, Hb);

    // L0: agg (unscaled Hb: gather dis) -> AGG(d_out), st0
    k_agg<false><<<N_ / 16, 256, 0, stream>>>(Hb, row_ptr, csr_src, dis, bs,
                                              (float4*)AGG, stats2);
    // L1: gemm(AGG | affine0+relu -> XBh) -> dis-scaled Hb ; agg -> AGG, st1
    k_gemm<<<GG, 256, 0, stream>>>(AGG, Wb + 16384, dis, Hb,
                                   stats2, gammas, betas, nullptr, XBh);
    k_agg<true><<<N_ / 16, 256, 0, stream>>>(Hb, row_ptr, csr_src, dis, bs + D_,
                                             (float4*)AGG, stats2 + 2048);
    // L2: gemm(AGG | affine1+relu + res XBh -> XBh) -> dis-scaled Hb ; agg -> AGG, st2
    k_gemm<<<GG, 256, 0, stream>>>(AGG, Wb + 32768, dis, Hb,
                                   stats2 + 2048, gammas + D_, betas + D_, XBh, XBh);
    k_agg<true><<<N_ / 16, 256, 0, stream>>>(Hb, row_ptr, csr_src, dis, bs + 2 * D_,
                                             (float4*)AGG, stats2 + 4096);
    // final: out = x2 + affine2(AGG)   (in-place on d_out)
    k_normF<<<1024, 256, 0, stream>>>((const float4*)AGG, XBh,
                                      stats2 + 4096, gammas + 2 * D_, betas + 2 * D_,
                                      (float4*)out);
}